// Round 11
// baseline (37.953 us; speedup 1.0000x reference)
//
#include <hip/hip_runtime.h>
#include <math.h>

// Problem constants (B=4, S=2048, D=1024, C=10)
constexpr int D_DIM = 1024;
constexpr int C_DIM = 10;
constexpr int WAVES = 4;            // waves per block
constexpr int TPW   = 2;            // tokens per wave (pipelined)
constexpr int TPB   = WAVES * TPW;  // 8 tokens per block
constexpr int BLOCK = 64 * WAVES;   // 256 threads

constexpr float CLAMP_V  = 1.0e6f;
constexpr float LOG2E    = 1.4426950408889634f;
constexpr float LN2      = 0.6931471805599453f;
constexpr float INV_2PI  = 0.15915494309189535f;

// float2 helpers -> coax v_pk_{fma,mul,add}_f32
__device__ __forceinline__ float2 pmul(float2 a, float2 b) {
    return make_float2(a.x * b.x, a.y * b.y);
}
__device__ __forceinline__ float2 pfma(float2 a, float2 b, float2 c) {
    return make_float2(fmaf(a.x, b.x, c.x), fmaf(a.y, b.y, c.y));
}
__device__ __forceinline__ float2 padd(float2 a, float2 b) {
    return make_float2(a.x + b.x, a.y + b.y);
}
__device__ __forceinline__ float2 bc(float s) { return make_float2(s, s); }

// wave-uniform value -> SGPR
__device__ __forceinline__ float rfl(float x) {
    return __int_as_float(__builtin_amdgcn_readfirstlane(__float_as_int(x)));
}

// ---- DPP wave64 sum -> SGPR (full-rate VALU, no LDS pipe) ----
template <int CTRL>
__device__ __forceinline__ float dpp_add(float v) {
    const int s = __builtin_amdgcn_update_dpp(
        0, __float_as_int(v), CTRL, 0xf, 0xf, false);
    return v + __int_as_float(s);
}
__device__ __forceinline__ float wave_sum_sgpr(float v) {
    v = dpp_add<0x111>(v);   // row_shr:1
    v = dpp_add<0x112>(v);   // row_shr:2
    v = dpp_add<0x114>(v);   // row_shr:4
    v = dpp_add<0x118>(v);   // row_shr:8
    v = dpp_add<0x142>(v);   // row_bcast:15
    v = dpp_add<0x143>(v);   // row_bcast:31 -> lane 63 = total
    return __int_as_float(__builtin_amdgcn_readlane(__float_as_int(v), 63));
}

struct Cst {
    float a0, a1, k2, o2, k3, o3, k4, o4, v5, a6, k7, o7, k8, o8, k9, o9, m9;
};

// Full per-token tail: normalize, candidate pass, joint-LN stats, write.
// All inputs wave-uniform except xv. acc reuses xn in place.
__device__ __forceinline__ void token_tail(
    const float4 xv[4], int lane, float mu, float rstd,
    const float w[C_DIM], float accbase, const Cst& C,
    const float* __restrict__ ln_gamma, const float* __restrict__ ln_beta,
    float* __restrict__ orow)
{
    float2 xn[8];
#pragma unroll
    for (int k = 0; k < 4; ++k) {
        const float4 gv = *reinterpret_cast<const float4*>(ln_gamma + k * 256 + (lane << 2));
        const float4 bv = *reinterpret_cast<const float4*>(ln_beta  + k * 256 + (lane << 2));
        const float2 zlo = pmul(padd(make_float2(xv[k].x, xv[k].y), bc(-mu)), bc(rstd));
        const float2 zhi = pmul(padd(make_float2(xv[k].z, xv[k].w), bc(-mu)), bc(rstd));
        xn[2 * k]     = pfma(zlo, make_float2(gv.x, gv.y), make_float2(bv.x, bv.y));
        xn[2 * k + 1] = pfma(zhi, make_float2(gv.z, gv.w), make_float2(bv.z, bv.w));
    }

    float2 S1 = bc(0.0f), S2 = bc(0.0f);
#pragma unroll
    for (int p = 0; p < 8; ++p) {
        const float2 xj = xn[p];
        const float2 ax = make_float2(fabsf(xj.x), fabsf(xj.y));
        const float2 x2 = pmul(xj, xj);

        const float2 v0 = pmul(bc(C.a0), xj);
        const float2 v1 = pmul(bc(C.a1), x2);

        float2 u2 = pmul(bc(C.k2), xj);
        u2 = padd(u2, make_float2(-rintf(u2.x), -rintf(u2.y)));
        const float2 v2 = pmul(bc(C.o2),
            make_float2(__builtin_amdgcn_cosf(u2.x), __builtin_amdgcn_cosf(u2.y)));

        float2 u3 = pmul(bc(C.k3), xj);
        u3 = padd(u3, make_float2(-rintf(u3.x), -rintf(u3.y)));
        const float2 v3 = pmul(bc(C.o3),
            make_float2(__builtin_amdgcn_sinf(u3.x), __builtin_amdgcn_sinf(u3.y)));

        const float2 u4 = pmul(bc(C.k4), xj);
        float2 v4 = pmul(bc(C.o4),
            make_float2(__builtin_amdgcn_exp2f(u4.x), __builtin_amdgcn_exp2f(u4.y)));
        v4 = make_float2(fminf(v4.x, CLAMP_V), fminf(v4.y, CLAMP_V));

        const float2 v6 = pmul(bc(C.a6), pmul(x2, xj));

        const float2 u7 = pfma(bc(C.k7), ax, bc(1.0f));
        const float2 v7 = pmul(bc(C.o7),
            make_float2(__builtin_amdgcn_logf(u7.x), __builtin_amdgcn_logf(u7.y)));

        const float2 u8 = pmul(bc(C.k8), ax);
        const float2 v8 = pmul(bc(C.o8),
            make_float2(__builtin_amdgcn_sqrtf(u8.x), __builtin_amdgcn_sqrtf(u8.y)));

        const float2 u9 = pmul(bc(C.k9), xj);
        const float2 e9 = padd(
            make_float2(__builtin_amdgcn_exp2f(u9.x), __builtin_amdgcn_exp2f(u9.y)),
            bc(1.0f));
        const float2 v9 = pfma(bc(C.m9),
            make_float2(__builtin_amdgcn_rcpf(e9.x), __builtin_amdgcn_rcpf(e9.y)),
            bc(C.o9));

        S1 = padd(S1, padd(padd(padd(v0, v1), padd(v2, v3)),
                           padd(padd(v4, v6), padd(padd(v7, v8), v9))));
        S2 = pfma(v0, v0, S2); S2 = pfma(v1, v1, S2); S2 = pfma(v2, v2, S2);
        S2 = pfma(v3, v3, S2); S2 = pfma(v4, v4, S2); S2 = pfma(v6, v6, S2);
        S2 = pfma(v7, v7, S2); S2 = pfma(v8, v8, S2); S2 = pfma(v9, v9, S2);

        float2 a = bc(accbase);
        a = pfma(bc(w[0]), v0, a); a = pfma(bc(w[1]), v1, a);
        a = pfma(bc(w[2]), v2, a); a = pfma(bc(w[3]), v3, a);
        a = pfma(bc(w[4]), v4, a); a = pfma(bc(w[6]), v6, a);
        a = pfma(bc(w[7]), v7, a); a = pfma(bc(w[8]), v8, a);
        a = pfma(bc(w[9]), v9, a);
        xn[p] = a;                 // in-place: xn[p] now holds acc
    }

    const float s1 = wave_sum_sgpr(S1.x + S1.y + 16.0f * C.v5);
    const float s2 = wave_sum_sgpr(fmaf(16.0f * C.v5, C.v5, S2.x + S2.y));

    constexpr float rn = 1.0f / (float)(C_DIM * D_DIM);
    const float mu2  = s1 * rn;
    const float var2 = s2 * rn - mu2 * mu2;
    const float rsig = rfl(rsqrtf(var2 + 1e-5f));

#pragma unroll
    for (int k = 0; k < 4; ++k) {
        const float2 lo = pmul(padd(xn[2 * k],     bc(-mu2)), bc(rsig));
        const float2 hi = pmul(padd(xn[2 * k + 1], bc(-mu2)), bc(rsig));
        float4 o;
        o.x = lo.x; o.y = lo.y; o.z = hi.x; o.w = hi.y;
        *reinterpret_cast<float4*>(orow + k * 256 + (lane << 2)) = o;
    }
}

__global__ __launch_bounds__(BLOCK)   // natural allocation (forcing spills: r5/r7)
void fused_sme_kernel(const float* __restrict__ x,
                      const float* __restrict__ ln_gamma,
                      const float* __restrict__ ln_beta,
                      const float* __restrict__ log_in_scale,
                      const float* __restrict__ log_out_scale,
                      const float* __restrict__ gate_w,
                      const float* __restrict__ gate_b,
                      float* __restrict__ out_weighted,   // (tokens, D)
                      float* __restrict__ out_gate,       // (tokens, C)
                      int tokens)
{
    const int t    = threadIdx.x;
    const int lane = t & 63;
    const int wv   = t >> 6;
    int tokA = blockIdx.x * TPB + wv * TPW;
    tokA = min(tokA, tokens - 1);
    const int tokB = min(tokA + 1, tokens - 1);

    __shared__ float gws[C_DIM * D_DIM];    // 40 KB: whole gate_w per block

    // ---- both tokens' x loads issue up front (B's latency hides under A) ----
    const float* xrowA = x + (size_t)tokA * D_DIM + (lane << 2);
    const float* xrowB = x + (size_t)tokB * D_DIM + (lane << 2);
    float4 xvA[4], xvB[4];
#pragma unroll
    for (int k = 0; k < 4; ++k) xvA[k] = *reinterpret_cast<const float4*>(xrowA + k * 256);
#pragma unroll
    for (int k = 0; k < 4; ++k) xvB[k] = *reinterpret_cast<const float4*>(xrowB + k * 256);

    // ---- cooperative gate_w stage: 2560 float4 over 256 threads ----
#pragma unroll
    for (int i = 0; i < 10; ++i) {
        const int idx = t + i * BLOCK;
        reinterpret_cast<float4*>(gws)[idx] =
            reinterpret_cast<const float4*>(gate_w)[idx];
    }

    // ---- LN partials for A and B (independent chains; overlap staging) ----
    float rA[12], rB[12];
    {
        float2 sA = bc(0.0f), qA = bc(0.0f), sB = bc(0.0f), qB = bc(0.0f);
#pragma unroll
        for (int k = 0; k < 4; ++k) {
            const float2 alo = make_float2(xvA[k].x, xvA[k].y);
            const float2 ahi = make_float2(xvA[k].z, xvA[k].w);
            sA = padd(sA, padd(alo, ahi));
            qA = pfma(alo, alo, qA); qA = pfma(ahi, ahi, qA);
            const float2 blo = make_float2(xvB[k].x, xvB[k].y);
            const float2 bhi = make_float2(xvB[k].z, xvB[k].w);
            sB = padd(sB, padd(blo, bhi));
            qB = pfma(blo, blo, qB); qB = pfma(bhi, bhi, qB);
        }
        rA[0] = wave_sum_sgpr(sA.x + sA.y);
        rA[1] = wave_sum_sgpr(qA.x + qA.y);
        rB[0] = wave_sum_sgpr(sB.x + sB.y);
        rB[1] = wave_sum_sgpr(qB.x + qB.y);
    }

    __syncthreads();      // gate_w resident

    // ---- gate dots: one ds_read per row chunk feeds BOTH tokens ----
#pragma unroll
    for (int c = 0; c < C_DIM; ++c) {
        const float* gr = gws + c * D_DIM + (lane << 2);
        float2 dA = bc(0.0f), dB = bc(0.0f);
#pragma unroll
        for (int k = 0; k < 4; ++k) {
            const float4 gv = *reinterpret_cast<const float4*>(gr + k * 256);
            const float2 glo = make_float2(gv.x, gv.y);
            const float2 ghi = make_float2(gv.z, gv.w);
            dA = pfma(make_float2(xvA[k].x, xvA[k].y), glo, dA);
            dA = pfma(make_float2(xvA[k].z, xvA[k].w), ghi, dA);
            dB = pfma(make_float2(xvB[k].x, xvB[k].y), glo, dB);
            dB = pfma(make_float2(xvB[k].z, xvB[k].w), ghi, dB);
        }
        rA[2 + c] = wave_sum_sgpr(dA.x + dA.y);
        rB[2 + c] = wave_sum_sgpr(dB.x + dB.y);
    }

    // ---- LN stats (SGPR) ----
    const float muA   = rA[0] * (1.0f / D_DIM);
    const float rstdA = rfl(rsqrtf(rA[1] * (1.0f / D_DIM) - muA * muA + 1e-5f));
    const float muB   = rB[0] * (1.0f / D_DIM);
    const float rstdB = rfl(rsqrtf(rB[1] * (1.0f / D_DIM) - muB * muB + 1e-5f));

    // ---- gate softmax for A and B (wave-uniform) ----
    float wA[C_DIM], wB[C_DIM];
    float gmA = -3.4e38f, gmB = -3.4e38f;
#pragma unroll
    for (int c = 0; c < C_DIM; ++c) {
        const float b = gate_b[c];
        wA[c] = rA[2 + c] + b; gmA = fmaxf(gmA, wA[c]);
        wB[c] = rB[2 + c] + b; gmB = fmaxf(gmB, wB[c]);
    }
    float esA = 0.0f, esB = 0.0f;
#pragma unroll
    for (int c = 0; c < C_DIM; ++c) {
        wA[c] = __builtin_amdgcn_exp2f((wA[c] - gmA) * LOG2E); esA += wA[c];
        wB[c] = __builtin_amdgcn_exp2f((wB[c] - gmB) * LOG2E); esB += wB[c];
    }
    const float rsA = __builtin_amdgcn_rcpf(esA);
    const float rsB = __builtin_amdgcn_rcpf(esB);
#pragma unroll
    for (int c = 0; c < C_DIM; ++c) {
        wA[c] = rfl(wA[c] * rsA);
        wB[c] = rfl(wB[c] * rsB);
    }
    if (lane < C_DIM) {
        out_gate[tokA * C_DIM + lane] = wA[lane];
        out_gate[tokB * C_DIM + lane] = wB[lane];
    }

    // ---- shared scales (one-time; SGPR via rfl) ----
    float in_s[C_DIM], out_s[C_DIM];
#pragma unroll
    for (int c = 0; c < C_DIM; ++c) {
        in_s[c]  = __builtin_amdgcn_exp2f(log_in_scale[c]  * LOG2E);
        out_s[c] = __builtin_amdgcn_exp2f(log_out_scale[c] * LOG2E);
    }
    Cst C;
    C.a0 = rfl(out_s[0] * in_s[0]);
    C.a1 = rfl(out_s[1] * in_s[1] * in_s[1]);
    C.k2 = rfl(in_s[2]);           C.o2 = rfl(out_s[2]);
    C.k3 = rfl(in_s[3] * INV_2PI); C.o3 = rfl(out_s[3]);
    C.k4 = rfl(in_s[4] * LOG2E);   C.o4 = rfl(out_s[4]);
    C.v5 = rfl(fminf(out_s[5], CLAMP_V));
    C.a6 = rfl(out_s[6] * in_s[6] * in_s[6] * in_s[6]);
    C.k7 = rfl(in_s[7]);           C.o7 = rfl(out_s[7] * LN2);
    C.k8 = rfl(in_s[8]);           C.o8 = rfl(out_s[8]);
    C.k9 = rfl(2.0f * in_s[9] * LOG2E);
    C.o9 = rfl(out_s[9]);          C.m9 = rfl(-2.0f * out_s[9]);

    // ---- token A tail (B's regs idle but resident; A's store drains under B) ----
    token_tail(xvA, lane, muA, rstdA, wA, rfl(wA[5] * C.v5), C,
               ln_gamma, ln_beta, out_weighted + (size_t)tokA * D_DIM);
    // ---- token B tail ----
    token_tail(xvB, lane, muB, rstdB, wB, rfl(wB[5] * C.v5), C,
               ln_gamma, ln_beta, out_weighted + (size_t)tokB * D_DIM);
}

extern "C" void kernel_launch(void* const* d_in, const int* in_sizes, int n_in,
                              void* d_out, int out_size, void* d_ws, size_t ws_size,
                              hipStream_t stream) {
    const float* x   = (const float*)d_in[0];
    const float* lg  = (const float*)d_in[1];
    const float* lb  = (const float*)d_in[2];
    const float* lis = (const float*)d_in[3];
    const float* los = (const float*)d_in[4];
    const float* gw  = (const float*)d_in[5];
    const float* gb  = (const float*)d_in[6];

    const int tokens = in_sizes[0] / D_DIM;   // B*S = 8192
    float* out      = (float*)d_out;
    float* out_gate = out + (size_t)tokens * D_DIM;

    const int grid = (tokens + TPB - 1) / TPB;
    hipLaunchKernelGGL(fused_sme_kernel, dim3(grid), dim3(BLOCK), 0, stream,
                       x, lg, lb, lis, los, gw, gb, out, out_gate, tokens);
}

// Round 12
// 30.489 us; speedup vs baseline: 1.2448x; 1.2448x over previous
//
#include <hip/hip_runtime.h>
#include <math.h>

// Problem constants (B=4, S=2048, D=1024, C=10)
constexpr int D_DIM = 1024;
constexpr int C_DIM = 10;
constexpr int WPB   = 8;            // waves (tokens) per block
constexpr int BLOCK = 64 * WPB;     // 512 threads

constexpr float CLAMP_V  = 1.0e6f;
constexpr float LOG2E    = 1.4426950408889634f;
constexpr float LN2      = 0.6931471805599453f;
constexpr float INV_2PI  = 0.15915494309189535f;

// float2 helpers -> coax v_pk_{fma,mul,add}_f32
__device__ __forceinline__ float2 pmul(float2 a, float2 b) {
    return make_float2(a.x * b.x, a.y * b.y);
}
__device__ __forceinline__ float2 pfma(float2 a, float2 b, float2 c) {
    return make_float2(fmaf(a.x, b.x, c.x), fmaf(a.y, b.y, c.y));
}
__device__ __forceinline__ float2 padd(float2 a, float2 b) {
    return make_float2(a.x + b.x, a.y + b.y);
}
__device__ __forceinline__ float2 bc(float s) { return make_float2(s, s); }

// wave-uniform value -> SGPR
__device__ __forceinline__ float rfl(float x) {
    return __int_as_float(__builtin_amdgcn_readfirstlane(__float_as_int(x)));
}

// ---- DPP wave64 sum -> SGPR (full-rate VALU, no LDS pipe) ----
template <int CTRL>
__device__ __forceinline__ float dpp_add(float v) {
    const int s = __builtin_amdgcn_update_dpp(
        0, __float_as_int(v), CTRL, 0xf, 0xf, false);
    return v + __int_as_float(s);
}
__device__ __forceinline__ float wave_sum_sgpr(float v) {
    v = dpp_add<0x111>(v);   // row_shr:1
    v = dpp_add<0x112>(v);   // row_shr:2
    v = dpp_add<0x114>(v);   // row_shr:4
    v = dpp_add<0x118>(v);   // row_shr:8
    v = dpp_add<0x142>(v);   // row_bcast:15
    v = dpp_add<0x143>(v);   // row_bcast:31 -> lane 63 = total
    return __int_as_float(__builtin_amdgcn_readlane(__float_as_int(v), 63));
}

__global__ __launch_bounds__(BLOCK)   // natural allocation (forcing spills: r5/r7)
void fused_sme_kernel(const float* __restrict__ x,
                      const float* __restrict__ ln_gamma,
                      const float* __restrict__ ln_beta,
                      const float* __restrict__ log_in_scale,
                      const float* __restrict__ log_out_scale,
                      const float* __restrict__ gate_w,
                      const float* __restrict__ gate_b,
                      float* __restrict__ out_weighted,   // (tokens, D)
                      float* __restrict__ out_gate,       // (tokens, C)
                      int tokens)
{
    const int t    = threadIdx.x;
    const int lane = t & 63;
    const int wv   = t >> 6;
    int token = blockIdx.x * WPB + wv;
    token = min(token, tokens - 1);         // no early return: barriers below

    __shared__ float gws[C_DIM * D_DIM];    // 40 KB: gate_w, later reused for acc

    // ---- this wave's 16 x-elements: d = k*256 + lane*4 (coalesced f4) ----
    const float* xrow = x + (size_t)token * D_DIM + (lane << 2);
    float4 xv[4];
#pragma unroll
    for (int k = 0; k < 4; ++k)
        xv[k] = *reinterpret_cast<const float4*>(xrow + k * 256);

    // ---- cooperative gate_w stage: 2560 float4 over 512 threads ----
#pragma unroll
    for (int i = 0; i < 5; ++i) {
        const int idx = t + i * BLOCK;
        reinterpret_cast<float4*>(gws)[idx] =
            reinterpret_cast<const float4*>(gate_w)[idx];
    }

    // ---- LN partials (overlap with staging latency) ----
    float r[12];
    {
        float2 s = bc(0.0f), q = bc(0.0f);
#pragma unroll
        for (int k = 0; k < 4; ++k) {
            const float2 lo = make_float2(xv[k].x, xv[k].y);
            const float2 hi = make_float2(xv[k].z, xv[k].w);
            s = padd(s, padd(lo, hi));
            q = pfma(lo, lo, q);
            q = pfma(hi, hi, q);
        }
        r[0] = wave_sum_sgpr(s.x + s.y);
        r[1] = wave_sum_sgpr(q.x + q.y);
    }

    __syncthreads();      // #1: gate_w resident in LDS

    // ---- gate dots from LDS (ds_read_b128, conflict-free) ----
#pragma unroll
    for (int c = 0; c < C_DIM; ++c) {
        const float* gr = gws + c * D_DIM + (lane << 2);
        float2 d2 = bc(0.0f);
#pragma unroll
        for (int k = 0; k < 4; ++k) {
            const float4 gv = *reinterpret_cast<const float4*>(gr + k * 256);
            d2 = pfma(make_float2(xv[k].x, xv[k].y), make_float2(gv.x, gv.y), d2);
            d2 = pfma(make_float2(xv[k].z, xv[k].w), make_float2(gv.z, gv.w), d2);
        }
        r[2 + c] = wave_sum_sgpr(d2.x + d2.y);
    }

    __syncthreads();      // #2: all gws reads done -> region reusable for acc

    // ---- input LayerNorm stats (SGPR) ----
    const float mu   = r[0] * (1.0f / D_DIM);
    const float var  = r[1] * (1.0f / D_DIM) - mu * mu;
    const float rstd = rfl(rsqrtf(var + 1e-5f));

    // ---- gate softmax (wave-uniform) ----
    float w[C_DIM];
    float gmax = -3.4e38f;
#pragma unroll
    for (int c = 0; c < C_DIM; ++c) {
        w[c] = r[2 + c] + gate_b[c];
        gmax = fmaxf(gmax, w[c]);
    }
    float esum = 0.0f;
#pragma unroll
    for (int c = 0; c < C_DIM; ++c) {
        w[c] = __builtin_amdgcn_exp2f((w[c] - gmax) * LOG2E);
        esum += w[c];
    }
    const float rsum = __builtin_amdgcn_rcpf(esum);
#pragma unroll
    for (int c = 0; c < C_DIM; ++c) w[c] = rfl(w[c] * rsum);

    // gate output store early: overlaps with the candidate pass
    if (lane < C_DIM) out_gate[token * C_DIM + lane] = w[lane];

    // ---- scales (grid-uniform; one-time; SGPR via rfl) ----
    float in_s[C_DIM], out_s[C_DIM];
#pragma unroll
    for (int c = 0; c < C_DIM; ++c) {
        in_s[c]  = __builtin_amdgcn_exp2f(log_in_scale[c]  * LOG2E);
        out_s[c] = __builtin_amdgcn_exp2f(log_out_scale[c] * LOG2E);
    }
    // derived constants; |xn| <= ~42 => only exp's output clamp can fire
    const float a0 = rfl(out_s[0] * in_s[0]);
    const float a1 = rfl(out_s[1] * in_s[1] * in_s[1]);
    const float k2 = rfl(in_s[2]),           o2 = rfl(out_s[2]);
    const float k3 = rfl(in_s[3] * INV_2PI), o3 = rfl(out_s[3]);
    const float k4 = rfl(in_s[4] * LOG2E),   o4 = rfl(out_s[4]);
    const float v5 = rfl(fminf(out_s[5], CLAMP_V));
    const float a6 = rfl(out_s[6] * in_s[6] * in_s[6] * in_s[6]);
    const float k7 = rfl(in_s[7]),           o7 = rfl(out_s[7] * LN2);
    const float k8 = rfl(in_s[8]),           o8 = rfl(out_s[8]);
    const float k9 = rfl(2.0f * in_s[9] * LOG2E);
    const float o9 = rfl(out_s[9]),          m9 = rfl(-2.0f * out_s[9]);

    // ---- normalized x overwrites xv in place (no VGPR growth) ----
    float2 xn[8];
#pragma unroll
    for (int k = 0; k < 4; ++k) {
        const float4 gv = *reinterpret_cast<const float4*>(ln_gamma + k * 256 + (lane << 2));
        const float4 bv = *reinterpret_cast<const float4*>(ln_beta  + k * 256 + (lane << 2));
        const float2 zlo = pmul(padd(make_float2(xv[k].x, xv[k].y), bc(-mu)), bc(rstd));
        const float2 zhi = pmul(padd(make_float2(xv[k].z, xv[k].w), bc(-mu)), bc(rstd));
        xn[2 * k]     = pfma(zlo, make_float2(gv.x, gv.y), make_float2(bv.x, bv.y));
        xn[2 * k + 1] = pfma(zhi, make_float2(gv.z, gv.w), make_float2(bv.z, bv.w));
    }

    // per-wave private acc slice in the dead gws region (pair-major, b64:
    // lane l byte = wv*4096 + p*512 + l*8 -> 2-way bank alias = free)
    float2* accw = reinterpret_cast<float2*>(gws + (wv << 10));

    // ---- candidate pass: stats + gated acc -> LDS (frees 16 VGPR) ----
    const float accbase = rfl(w[5] * v5);
    float2 S1 = bc(0.0f), S2 = bc(0.0f);

#pragma unroll
    for (int p = 0; p < 8; ++p) {
        const float2 xj = xn[p];
        const float2 ax = make_float2(fabsf(xj.x), fabsf(xj.y));
        const float2 x2 = pmul(xj, xj);

        const float2 v0 = pmul(bc(a0), xj);
        const float2 v1 = pmul(bc(a1), x2);

        float2 u2 = pmul(bc(k2), xj);
        u2 = padd(u2, make_float2(-rintf(u2.x), -rintf(u2.y)));
        const float2 v2 = pmul(bc(o2),
            make_float2(__builtin_amdgcn_cosf(u2.x), __builtin_amdgcn_cosf(u2.y)));

        float2 u3 = pmul(bc(k3), xj);
        u3 = padd(u3, make_float2(-rintf(u3.x), -rintf(u3.y)));
        const float2 v3 = pmul(bc(o3),
            make_float2(__builtin_amdgcn_sinf(u3.x), __builtin_amdgcn_sinf(u3.y)));

        const float2 u4 = pmul(bc(k4), xj);
        float2 v4 = pmul(bc(o4),
            make_float2(__builtin_amdgcn_exp2f(u4.x), __builtin_amdgcn_exp2f(u4.y)));
        v4 = make_float2(fminf(v4.x, CLAMP_V), fminf(v4.y, CLAMP_V));

        const float2 v6 = pmul(bc(a6), pmul(x2, xj));

        const float2 u7 = pfma(bc(k7), ax, bc(1.0f));
        const float2 v7 = pmul(bc(o7),
            make_float2(__builtin_amdgcn_logf(u7.x), __builtin_amdgcn_logf(u7.y)));

        const float2 u8 = pmul(bc(k8), ax);
        const float2 v8 = pmul(bc(o8),
            make_float2(__builtin_amdgcn_sqrtf(u8.x), __builtin_amdgcn_sqrtf(u8.y)));

        const float2 u9 = pmul(bc(k9), xj);
        const float2 e9 = padd(
            make_float2(__builtin_amdgcn_exp2f(u9.x), __builtin_amdgcn_exp2f(u9.y)),
            bc(1.0f));
        const float2 v9 = pfma(bc(m9),
            make_float2(__builtin_amdgcn_rcpf(e9.x), __builtin_amdgcn_rcpf(e9.y)),
            bc(o9));

        S1 = padd(S1, padd(padd(padd(v0, v1), padd(v2, v3)),
                           padd(padd(v4, v6), padd(padd(v7, v8), v9))));
        S2 = pfma(v0, v0, S2); S2 = pfma(v1, v1, S2); S2 = pfma(v2, v2, S2);
        S2 = pfma(v3, v3, S2); S2 = pfma(v4, v4, S2); S2 = pfma(v6, v6, S2);
        S2 = pfma(v7, v7, S2); S2 = pfma(v8, v8, S2); S2 = pfma(v9, v9, S2);

        float2 a = bc(accbase);
        a = pfma(bc(w[0]), v0, a); a = pfma(bc(w[1]), v1, a);
        a = pfma(bc(w[2]), v2, a); a = pfma(bc(w[3]), v3, a);
        a = pfma(bc(w[4]), v4, a); a = pfma(bc(w[6]), v6, a);
        a = pfma(bc(w[7]), v7, a); a = pfma(bc(w[8]), v8, a);
        a = pfma(bc(w[9]), v9, a);
        accw[(p << 6) + lane] = a;          // ds_write_b64, wave-private slice
    }

    // c5 stats contribution (16 elements per lane)
    const float s1 = wave_sum_sgpr(S1.x + S1.y + 16.0f * v5);
    const float s2 = wave_sum_sgpr(fmaf(16.0f * v5, v5, S2.x + S2.y));

    constexpr float rn = 1.0f / (float)(C_DIM * D_DIM);
    const float mu2  = s1 * rn;
    const float var2 = s2 * rn - mu2 * mu2;
    const float rsig = rfl(rsqrtf(var2 + 1e-5f));

    // ---- read acc back, scale, write outputs ----
    float* orow = out_weighted + (size_t)token * D_DIM + (lane << 2);
#pragma unroll
    for (int k = 0; k < 4; ++k) {
        const float2 lo = pmul(padd(accw[((2 * k)     << 6) + lane], bc(-mu2)), bc(rsig));
        const float2 hi = pmul(padd(accw[((2 * k + 1) << 6) + lane], bc(-mu2)), bc(rsig));
        float4 o;
        o.x = lo.x; o.y = lo.y; o.z = hi.x; o.w = hi.y;
        *reinterpret_cast<float4*>(orow + k * 256) = o;
    }
}

extern "C" void kernel_launch(void* const* d_in, const int* in_sizes, int n_in,
                              void* d_out, int out_size, void* d_ws, size_t ws_size,
                              hipStream_t stream) {
    const float* x   = (const float*)d_in[0];
    const float* lg  = (const float*)d_in[1];
    const float* lb  = (const float*)d_in[2];
    const float* lis = (const float*)d_in[3];
    const float* los = (const float*)d_in[4];
    const float* gw  = (const float*)d_in[5];
    const float* gb  = (const float*)d_in[6];

    const int tokens = in_sizes[0] / D_DIM;   // B*S = 8192
    float* out      = (float*)d_out;
    float* out_gate = out + (size_t)tokens * D_DIM;

    const int grid = (tokens + WPB - 1) / WPB;
    hipLaunchKernelGGL(fused_sme_kernel, dim3(grid), dim3(BLOCK), 0, stream,
                       x, lg, lb, lis, los, gw, gb, out, out_gate, tokens);
}